// Round 1
// baseline (813.586 us; speedup 1.0000x reference)
//
#include <hip/hip_runtime.h>
#include <math.h>

// ---------------------------------------------------------------------------
// StaticGraphGNN: 3-layer GAT (PyG GATConv-style) + LayerNorm + ReLU, fp32.
// Strategy round 1 (correctness-first):
//   - Build CSR-by-dst on device each call (histogram -> scan -> scatter).
//   - Per layer: tiled fp32 GEMM (h = x @ W), per-node logits (als/ald),
//     wave-per-node online-softmax aggregation with fused bias+LN+ReLU.
// ---------------------------------------------------------------------------

__global__ void k_zero_i32(int* __restrict__ p, int n) {
  int i = blockIdx.x * blockDim.x + threadIdx.x;
  if (i < n) p[i] = 0;
}

__global__ void k_count_deg(const int* __restrict__ ei, int E, int N,
                            int* __restrict__ deg) {
  int t = blockIdx.x * blockDim.x + threadIdx.x;
  int tot = E + N;
  if (t >= tot) return;
  int d = (t < E) ? ei[E + t] : (t - E);  // self-loop tail
  atomicAdd(&deg[d], 1);
}

__global__ void k_block_sums(const int* __restrict__ deg, int* __restrict__ bsum,
                             int n) {
  __shared__ int s[256];
  int i = blockIdx.x * 256 + threadIdx.x;
  s[threadIdx.x] = (i < n) ? deg[i] : 0;
  __syncthreads();
  for (int off = 128; off > 0; off >>= 1) {
    if (threadIdx.x < off) s[threadIdx.x] += s[threadIdx.x + off];
    __syncthreads();
  }
  if (threadIdx.x == 0) bsum[blockIdx.x] = s[0];
}

// single block, exclusive scan of nb (<=256) block sums
__global__ void k_scan_bsums(int* __restrict__ bsum, int nb) {
  __shared__ int s[256];
  int t = threadIdx.x;
  int mine = (t < nb) ? bsum[t] : 0;
  s[t] = mine;
  __syncthreads();
  for (int off = 1; off < 256; off <<= 1) {
    int v = (t >= off) ? s[t - off] : 0;
    __syncthreads();
    s[t] += v;
    __syncthreads();
  }
  if (t < nb) bsum[t] = s[t] - mine;  // exclusive
}

__global__ void k_write_rowstart(const int* __restrict__ deg,
                                 const int* __restrict__ bofs,
                                 int* __restrict__ rowstart,
                                 int* __restrict__ cursor, int n, int total) {
  __shared__ int s[256];
  int t = threadIdx.x;
  int i = blockIdx.x * 256 + t;
  int mine = (i < n) ? deg[i] : 0;
  s[t] = mine;
  __syncthreads();
  for (int off = 1; off < 256; off <<= 1) {
    int v = (t >= off) ? s[t - off] : 0;
    __syncthreads();
    s[t] += v;
    __syncthreads();
  }
  if (i < n) {
    int r = bofs[blockIdx.x] + s[t] - mine;
    rowstart[i] = r;
    cursor[i] = r;
  }
  if (i == 0) rowstart[n] = total;
}

__global__ void k_scatter(const int* __restrict__ ei, int E, int N,
                          int* __restrict__ cursor, int* __restrict__ colidx) {
  int t = blockIdx.x * blockDim.x + threadIdx.x;
  int tot = E + N;
  if (t >= tot) return;
  int s, d;
  if (t < E) { s = ei[t]; d = ei[E + t]; } else { s = t - E; d = t - E; }
  int pos = atomicAdd(&cursor[d], 1);
  colidx[pos] = s;
}

// ---------------------------------------------------------------------------
// fp32 GEMM: C[M,Nc] = A[M,K] @ B[K,Nc].  64x64 tile / block, 256 threads,
// 4x4 outputs per thread, BK=16 staged in LDS. K % 16 == 0, Nc % 64 == 0.
// ---------------------------------------------------------------------------
__global__ __launch_bounds__(256) void k_gemm(const float* __restrict__ A,
                                              const float* __restrict__ B,
                                              float* __restrict__ C, int M,
                                              int K, int Nc) {
  __shared__ float As[16][68];  // [k][row], padded
  __shared__ float Bs[16][68];  // [k][col], padded
  int tid = threadIdx.x;
  int row0 = blockIdx.y * 64;
  int col0 = blockIdx.x * 64;
  int tx = tid & 15, ty = tid >> 4;
  float acc[4][4] = {};
  for (int k0 = 0; k0 < K; k0 += 16) {
    {  // A tile: 64 rows x 16 k, thread -> row=tid>>2, kchunk=(tid&3)*4
      int r = tid >> 2, kc = (tid & 3) * 4;
      int gr = row0 + r;
      float4 v = make_float4(0.f, 0.f, 0.f, 0.f);
      if (gr < M) v = *(const float4*)(A + (size_t)gr * K + k0 + kc);
      As[kc + 0][r] = v.x;
      As[kc + 1][r] = v.y;
      As[kc + 2][r] = v.z;
      As[kc + 3][r] = v.w;
    }
    {  // B tile: 16 k x 64 cols, thread -> k=tid>>4, cchunk=(tid&15)*4
      int kk = tid >> 4, c = (tid & 15) * 4;
      float4 v = *(const float4*)(B + (size_t)(k0 + kk) * Nc + col0 + c);
      *(float4*)&Bs[kk][c] = v;
    }
    __syncthreads();
#pragma unroll
    for (int kk = 0; kk < 16; kk++) {
      float4 a4 = *(const float4*)&As[kk][ty * 4];
      float4 b4 = *(const float4*)&Bs[kk][tx * 4];
      float a[4] = {a4.x, a4.y, a4.z, a4.w};
      float b[4] = {b4.x, b4.y, b4.z, b4.w};
#pragma unroll
      for (int i = 0; i < 4; i++)
#pragma unroll
        for (int j = 0; j < 4; j++) acc[i][j] += a[i] * b[j];
    }
    __syncthreads();
  }
#pragma unroll
  for (int i = 0; i < 4; i++) {
    int gr = row0 + ty * 4 + i;
    if (gr < M) {
      float4 v = make_float4(acc[i][0], acc[i][1], acc[i][2], acc[i][3]);
      *(float4*)(C + (size_t)gr * Nc + col0 + tx * 4) = v;
    }
  }
}

// ---------------------------------------------------------------------------
// Per-node attention logits: als[n,h] = sum_c h[n,h,c]*a_s[h,c]; same for ald.
// One wave per node; lane i owns channel i of every head.
// ---------------------------------------------------------------------------
template <int H>
__global__ void k_logits(const float* __restrict__ h, const float* __restrict__ a_s,
                         const float* __restrict__ a_d, float* __restrict__ als,
                         float* __restrict__ ald, int N) {
  int gw = (blockIdx.x * blockDim.x + threadIdx.x) >> 6;
  int lane = threadIdx.x & 63;
  if (gw >= N) return;
  const float* row = h + (size_t)gw * (H * 64);
  float vs[H], vd[H];
#pragma unroll
  for (int j = 0; j < H; j++) {
    float v = row[j * 64 + lane];
    vs[j] = v * a_s[j * 64 + lane];
    vd[j] = v * a_d[j * 64 + lane];
  }
#pragma unroll
  for (int j = 0; j < H; j++) {
    for (int msk = 32; msk > 0; msk >>= 1) {
      vs[j] += __shfl_xor(vs[j], msk, 64);
      vd[j] += __shfl_xor(vd[j], msk, 64);
    }
  }
  if (lane == 0) {
#pragma unroll
    for (int j = 0; j < H; j++) {
      als[(size_t)gw * H + j] = vs[j];
      ald[(size_t)gw * H + j] = vd[j];
    }
  }
}

// ---------------------------------------------------------------------------
// Wave-per-dst-node online-softmax aggregation. Lane i owns channel i of each
// head (HC = H*64 accumulators spread as H regs/lane). Fused bias (+LN+ReLU).
// ---------------------------------------------------------------------------
template <int H, bool LN>
__global__ void k_aggregate(const float* __restrict__ h,
                            const float* __restrict__ als,
                            const float* __restrict__ ald,
                            const int* __restrict__ rowstart,
                            const int* __restrict__ colidx,
                            const float* __restrict__ bias,
                            const float* __restrict__ ln_g,
                            const float* __restrict__ ln_b,
                            float* __restrict__ out, int N) {
  int node = (blockIdx.x * blockDim.x + threadIdx.x) >> 6;
  int lane = threadIdx.x & 63;
  if (node >= N) return;
  constexpr int HC = H * 64;
  float aldd[H];
#pragma unroll
  for (int j = 0; j < H; j++) aldd[j] = ald[(size_t)node * H + j];
  float m[H], l[H], acc[H];
#pragma unroll
  for (int j = 0; j < H; j++) {
    m[j] = -INFINITY;
    l[j] = 0.f;
    acc[j] = 0.f;
  }
  int e0 = rowstart[node], e1 = rowstart[node + 1];
  for (int e = e0; e < e1; e++) {
    int s = colidx[e];
    const float* hrow = h + (size_t)s * HC;
    float alsv[H];
    if constexpr (H == 4) {
      float4 t4 = *(const float4*)(als + (size_t)s * 4);
      alsv[0] = t4.x; alsv[1] = t4.y; alsv[2] = t4.z; alsv[3] = t4.w;
    } else {
      alsv[0] = als[s];
    }
#pragma unroll
    for (int j = 0; j < H; j++) {
      float lg = alsv[j] + aldd[j];
      lg = (lg > 0.f) ? lg : 0.2f * lg;  // leaky_relu 0.2
      float nm = fmaxf(m[j], lg);
      float sc = __expf(m[j] - nm);  // 0 on first edge (m=-inf)
      float p = __expf(lg - nm);
      l[j] = l[j] * sc + p;
      acc[j] = acc[j] * sc + p * hrow[j * 64 + lane];
      m[j] = nm;
    }
  }
  float y[H];
#pragma unroll
  for (int j = 0; j < H; j++)
    y[j] = acc[j] / (l[j] + 1e-16f) + bias[j * 64 + lane];
  if constexpr (LN) {
    float s1 = 0.f;
#pragma unroll
    for (int j = 0; j < H; j++) s1 += y[j];
    for (int msk = 32; msk > 0; msk >>= 1) s1 += __shfl_xor(s1, msk, 64);
    float mu = s1 * (1.0f / HC);
    float s2 = 0.f;
#pragma unroll
    for (int j = 0; j < H; j++) {
      float dv = y[j] - mu;
      s2 += dv * dv;
    }
    for (int msk = 32; msk > 0; msk >>= 1) s2 += __shfl_xor(s2, msk, 64);
    float rstd = rsqrtf(s2 * (1.0f / HC) + 1e-5f);
#pragma unroll
    for (int j = 0; j < H; j++) {
      float v = (y[j] - mu) * rstd * ln_g[j * 64 + lane] + ln_b[j * 64 + lane];
      out[(size_t)node * HC + j * 64 + lane] = fmaxf(v, 0.f);
    }
  } else {
#pragma unroll
    for (int j = 0; j < H; j++)
      out[(size_t)node * HC + j * 64 + lane] = y[j];
  }
}

// ---------------------------------------------------------------------------
extern "C" void kernel_launch(void* const* d_in, const int* in_sizes, int n_in,
                              void* d_out, int out_size, void* d_ws,
                              size_t ws_size, hipStream_t stream) {
  const float* x   = (const float*)d_in[0];
  const int*   ei  = (const int*)d_in[1];
  const float* W1  = (const float*)d_in[2];
  const float* a1s = (const float*)d_in[3];
  const float* a1d = (const float*)d_in[4];
  const float* b1  = (const float*)d_in[5];
  const float* g1  = (const float*)d_in[6];
  const float* be1 = (const float*)d_in[7];
  const float* W2  = (const float*)d_in[8];
  const float* a2s = (const float*)d_in[9];
  const float* a2d = (const float*)d_in[10];
  const float* b2  = (const float*)d_in[11];
  const float* g2  = (const float*)d_in[12];
  const float* be2 = (const float*)d_in[13];
  const float* W3  = (const float*)d_in[14];
  const float* a3s = (const float*)d_in[15];
  const float* a3d = (const float*)d_in[16];
  const float* b3  = (const float*)d_in[17];
  float* out = (float*)d_out;

  const int Nn = in_sizes[0] / 128;  // 50000
  const int E  = in_sizes[1] / 2;    // 800000
  const int ET = E + Nn;             // edges incl. self-loops

  char* wsb = (char*)d_ws;
  size_t off = 0;
  auto alloc = [&](size_t bytes) -> void* {
    void* p = wsb + off;
    off += (bytes + 255) & ~(size_t)255;
    return p;
  };
  float* hbuf = (float*)alloc((size_t)Nn * 256 * 4);
  float* xbuf = (float*)alloc((size_t)Nn * 256 * 4);
  float* als  = (float*)alloc((size_t)Nn * 4 * 4);
  float* ald  = (float*)alloc((size_t)Nn * 4 * 4);
  int* rowstart = (int*)alloc((size_t)(Nn + 1) * 4);
  int* cursor   = (int*)alloc((size_t)Nn * 4);
  int* deg      = (int*)alloc((size_t)Nn * 4);
  int* colidx   = (int*)alloc((size_t)ET * 4);
  int* bsum     = (int*)alloc(256 * 4);
  (void)ws_size;

  // ---- CSR by destination (rebuilt every call; same work per call) ----
  int nb = (Nn + 255) / 256;  // 196 <= 256
  k_zero_i32<<<nb, 256, 0, stream>>>(deg, Nn);
  k_count_deg<<<(ET + 255) / 256, 256, 0, stream>>>(ei, E, Nn, deg);
  k_block_sums<<<nb, 256, 0, stream>>>(deg, bsum, Nn);
  k_scan_bsums<<<1, 256, 0, stream>>>(bsum, nb);
  k_write_rowstart<<<nb, 256, 0, stream>>>(deg, bsum, rowstart, cursor, Nn, ET);
  k_scatter<<<(ET + 255) / 256, 256, 0, stream>>>(ei, E, Nn, cursor, colidx);

  int nwb = (Nn + 3) / 4;           // wave-per-node kernels, 4 waves/block
  dim3 gemmGrid4(4, (Nn + 63) / 64);
  dim3 gemmGrid1(1, (Nn + 63) / 64);

  // ---- Layer 1: [N,128] @ [128,256], H=4, LN+ReLU ----
  k_gemm<<<gemmGrid4, 256, 0, stream>>>(x, W1, hbuf, Nn, 128, 256);
  k_logits<4><<<nwb, 256, 0, stream>>>(hbuf, a1s, a1d, als, ald, Nn);
  k_aggregate<4, true><<<nwb, 256, 0, stream>>>(hbuf, als, ald, rowstart,
                                                colidx, b1, g1, be1, xbuf, Nn);
  // ---- Layer 2: [N,256] @ [256,256], H=4, LN+ReLU ----
  k_gemm<<<gemmGrid4, 256, 0, stream>>>(xbuf, W2, hbuf, Nn, 256, 256);
  k_logits<4><<<nwb, 256, 0, stream>>>(hbuf, a2s, a2d, als, ald, Nn);
  k_aggregate<4, true><<<nwb, 256, 0, stream>>>(hbuf, als, ald, rowstart,
                                                colidx, b2, g2, be2, xbuf, Nn);
  // ---- Layer 3: [N,256] @ [256,64], H=1, no LN ----
  k_gemm<<<gemmGrid1, 256, 0, stream>>>(xbuf, W3, hbuf, Nn, 256, 64);
  k_logits<1><<<nwb, 256, 0, stream>>>(hbuf, a3s, a3d, als, ald, Nn);
  k_aggregate<1, false><<<nwb, 256, 0, stream>>>(hbuf, als, ald, rowstart,
                                                 colidx, b3, nullptr, nullptr,
                                                 out, Nn);
}